// Round 1
// baseline (187.520 us; speedup 1.0000x reference)
//
#include <hip/hip_runtime.h>

// LogSumExpPooling2D: x (8,256,256,64) f32 NHWC ->
// out (1,128,128,64): (1/100)*logsumexp(100*x) over 2x2 stride-2 window AND batch.
// Memory-bound: 128 MiB read + 4 MiB write, ~21 us HBM floor @ 6.3-6.9 TB/s
// (possibly lower: input fits in 256 MiB L3 across bench iterations).
//
// R3: 4-way lane-split of the reduction.
//   lane bits: [3:0]=channel-group (c=cg*4), [4]=window column dw, [5]=batch half nh.
//   Each thread: 8 independent float4 loads (4 images x 2 rows of ONE column),
//   one max tree + one exp pass, then two __shfl_xor online-LSE merges
//   (lane^16 = dw partner, lane^32 = batch-half partner). Lanes 0-15 write.
// vs R2: grid 1024->4096 blocks (4->8 waves/SIMD resident), per-thread serial
//   chain of 4 dependent chunks -> 1 chunk of 8 back-to-back loads, and
//   coalescing segments widen 256B -> 512B (dw lanes adjacent).

constexpr float SCALE = 100.0f;
constexpr float INV_SCALE = 0.01f;

__global__ __launch_bounds__(256, 8) void lse_pool_kernel(const float* __restrict__ x,
                                                          float* __restrict__ out) {
    const int t   = blockIdx.x * 256 + threadIdx.x;  // 0 .. 1048575
    const int cg  = t & 15;          // channel group of 4 (c = cg*4)
    const int dw  = (t >> 4) & 1;    // which input column of the 2x2 window
    const int nh  = (t >> 5) & 1;    // batch half: images nh*4 .. nh*4+3
    const int pix = t >> 6;          // output pixel 0 .. 16383
    const int wo  = pix & 127;
    const int ho  = pix >> 7;

    const size_t NSTRIDE = (size_t)256 * 256 * 64;   // floats per image
    const size_t ROW     = (size_t)256 * 64;         // floats per input row

    // Per-wave address pattern per load instruction:
    //   lanes 0-31: 512B contiguous (cg x dw), lanes 32-63: same +4*NSTRIDE.
    const float* p = x + ((size_t)(ho << 1) * 256 + (size_t)((wo << 1) | dw)) * 64
                       + (size_t)(cg << 2)
                       + (size_t)nh * 4 * NSTRIDE;

    // 8 independent loads: k = n'<<1 | dh  (n' = image within half, dh = row)
    float4 v[8];
#pragma unroll
    for (int k = 0; k < 8; ++k) {
        v[k] = *reinterpret_cast<const float4*>(p + (size_t)(k >> 1) * NSTRIDE
                                                  + (size_t)(k & 1) * ROW);
    }

    // per-thread max over the 8 values, per channel
    float m[4] = { v[0].x, v[0].y, v[0].z, v[0].w };
#pragma unroll
    for (int k = 1; k < 8; ++k) {
        m[0] = fmaxf(m[0], v[k].x);
        m[1] = fmaxf(m[1], v[k].y);
        m[2] = fmaxf(m[2], v[k].z);
        m[3] = fmaxf(m[3], v[k].w);
    }

    // per-thread sum of exp(100*(v - m)); args <= 0, no overflow
    float s[4] = { 0.f, 0.f, 0.f, 0.f };
#pragma unroll
    for (int k = 0; k < 8; ++k) {
        s[0] += __expf((v[k].x - m[0]) * SCALE);
        s[1] += __expf((v[k].y - m[1]) * SCALE);
        s[2] += __expf((v[k].z - m[2]) * SCALE);
        s[3] += __expf((v[k].w - m[3]) * SCALE);
    }

    // cross-lane online-LSE merges: lane^16 (dw partner), lane^32 (batch half)
#pragma unroll
    for (int bit = 16; bit <= 32; bit <<= 1) {
#pragma unroll
        for (int j = 0; j < 4; ++j) {
            const float mo = __shfl_xor(m[j], bit);
            const float so = __shfl_xor(s[j], bit);
            const float mn = fmaxf(m[j], mo);
            s[j] = s[j] * __expf((m[j] - mn) * SCALE)
                 + so   * __expf((mo   - mn) * SCALE);
            m[j] = mn;
        }
    }

    // lanes with dw==0 && nh==0 (lanes 0-15) hold the full result: 256B/wave store
    if ((t & 48) == 0) {
        float4 r;
        r.x = m[0] + __logf(s[0]) * INV_SCALE;
        r.y = m[1] + __logf(s[1]) * INV_SCALE;
        r.z = m[2] + __logf(s[2]) * INV_SCALE;
        r.w = m[3] + __logf(s[3]) * INV_SCALE;
        *reinterpret_cast<float4*>(out + (size_t)pix * 64 + (size_t)(cg << 2)) = r;
    }
}

extern "C" void kernel_launch(void* const* d_in, const int* in_sizes, int n_in,
                              void* d_out, int out_size, void* d_ws, size_t ws_size,
                              hipStream_t stream) {
    const float* x = (const float*)d_in[0];
    float* out = (float*)d_out;
    // 16384 pixels * 64 lanes-of-work (16 cg x 2 dw x 2 nh) = 1048576 threads
    lse_pool_kernel<<<4096, 256, 0, stream>>>(x, out);
}